// Round 5
// baseline (277.208 us; speedup 1.0000x reference)
//
#include <hip/hip_runtime.h>
#include <hip/hip_bf16.h>
#include <cstddef>

typedef __bf16 bf16x8 __attribute__((ext_vector_type(8)));
typedef float f32x4 __attribute__((ext_vector_type(4)));

// ---------------- prep kernels ----------------

// x fp32 NCHW [8,512,8,8] -> bf16 NHWC [8,8,8,512]
__global__ void convert_x_kernel(const float* __restrict__ x, __hip_bfloat16* __restrict__ act0) {
    int t = blockIdx.x * 256 + threadIdx.x;          // 262144 total
    int c = t & 511; int rest = t >> 9;
    int w = rest & 7; rest >>= 3; int h = rest & 7; int b = rest >> 3;
    act0[t] = __float2bfloat16(x[((b * 512 + c) * 8 + h) * 8 + w]);
}

// All weight transposes fused: fp32 [CO][CI][3][3] -> bf16 [9][CO][CI] (x5) + final (CO padded 3->16)
__global__ void wtrans_all_kernel(const float* __restrict__ w1, __hip_bfloat16* __restrict__ o1,
                                  const float* __restrict__ w2, __hip_bfloat16* __restrict__ o2,
                                  const float* __restrict__ w3, __hip_bfloat16* __restrict__ o3,
                                  const float* __restrict__ w4, __hip_bfloat16* __restrict__ o4,
                                  const float* __restrict__ w5, __hip_bfloat16* __restrict__ o5,
                                  const float* __restrict__ wf, __hip_bfloat16* __restrict__ of) {
    int t = blockIdx.x * 256 + threadIdx.x;
    const float* w; __hip_bfloat16* o; int lgci, lgco; bool fin = false;
    if      (t < 1179648) { w = w1; o = o1; lgci = 9; lgco = 8; }
    else if (t < 1474560) { t -= 1179648; w = w2; o = o2; lgci = 8; lgco = 7; }
    else if (t < 1548288) { t -= 1474560; w = w3; o = o3; lgci = 7; lgco = 6; }
    else if (t < 1585152) { t -= 1548288; w = w4; o = o4; lgci = 6; lgco = 6; }
    else if (t < 1622016) { t -= 1585152; w = w5; o = o5; lgci = 6; lgco = 6; }
    else if (t < 1631232) { t -= 1622016; w = wf; o = of; lgci = 6; lgco = 4; fin = true; }
    else return;
    int CI = 1 << lgci;
    int ci = t & (CI - 1);
    int co = (t >> lgci) & ((1 << lgco) - 1);
    int tap = t >> (lgci + lgco);
    float v = 0.f;
    if (!fin || co < 3) v = w[((size_t)co * CI + ci) * 9 + tap];
    o[t] = __float2bfloat16(v);
}

// All style FCs fused. S: S1@0 (8x256), S2@2048, S3@3072, S4@3584, S5@4096.
__global__ void style_all_kernel(const float* __restrict__ style,
                                 const float* __restrict__ fw1, const float* __restrict__ fb1,
                                 const float* __restrict__ fw2, const float* __restrict__ fb2,
                                 const float* __restrict__ fw3, const float* __restrict__ fb3,
                                 const float* __restrict__ fw4, const float* __restrict__ fb4,
                                 const float* __restrict__ fw5, const float* __restrict__ fb5,
                                 float* __restrict__ S) {
    int wvid = blockIdx.x * 4 + (threadIdx.x >> 6);
    int lane = threadIdx.x & 63;
    const float* fw; const float* fb; int lg, sOff, local;
    if      (wvid < 2048) { fw = fw1; fb = fb1; lg = 8; sOff = 0;    local = wvid; }
    else if (wvid < 3072) { fw = fw2; fb = fb2; lg = 7; sOff = 2048; local = wvid - 2048; }
    else if (wvid < 3584) { fw = fw3; fb = fb3; lg = 6; sOff = 3072; local = wvid - 3072; }
    else if (wvid < 4096) { fw = fw4; fb = fb4; lg = 6; sOff = 3584; local = wvid - 3584; }
    else                  { fw = fw5; fb = fb5; lg = 6; sOff = 4096; local = wvid - 4096; }
    int b = local >> lg, o = local & ((1 << lg) - 1);
    const float* sb = style + b * 512;
    const float* fwo = fw + (size_t)o * 512;
    float p = 0.f;
    #pragma unroll
    for (int k = lane; k < 512; k += 64) p += sb[k] * fwo[k];
    #pragma unroll
    for (int off = 32; off > 0; off >>= 1) p += __shfl_down(p, off);
    if (lane == 0) S[sOff + local] = p + fb[o];
}

// Zero the 1-px halo border of act3p/act4p/act5p (ws is re-poisoned each call).
__global__ void halo_zero_kernel(__hip_bfloat16* __restrict__ a3,
                                 __hip_bfloat16* __restrict__ a4,
                                 __hip_bfloat16* __restrict__ a5) {
    int t = blockIdx.x * 256 + threadIdx.x;
    // a3: Hp=66 -> 260 px -> 16640 items; a4: 130 -> 516 -> 33024; a5: 258 -> 1028 -> 65792
    __hip_bfloat16* buf; int Hp, npx, loc;
    if      (t < 16640)                 { buf = a3; Hp = 66;  npx = 260;  loc = t; }
    else if (t < 16640 + 33024)         { buf = a4; Hp = 130; npx = 516;  loc = t - 16640; }
    else if (t < 16640 + 33024 + 65792) { buf = a5; Hp = 258; npx = 1028; loc = t - 49664; }
    else return;
    int oct = loc & 7; int rest = loc >> 3;
    int k = rest % npx; int b = rest / npx;
    int h, w;
    if (k < Hp)            { h = 0;        w = k; }
    else if (k < 2 * Hp)   { h = Hp - 1;   w = k - Hp; }
    else { int k2 = k - 2 * Hp; h = 1 + (k2 >> 1); w = (k2 & 1) ? (Hp - 1) : 0; }
    uint4 z = {0, 0, 0, 0};
    *(uint4*)(buf + ((size_t)(b * Hp + h) * Hp + w) * 64 + oct * 8) = z;
}

// ---------------- K-split partial conv (stages 1-3) ----------------
template <int CI, int CO, int HS, int WS>
__launch_bounds__(256)
__global__ void conv_partial_kernel(const __hip_bfloat16* __restrict__ actIn,
                                    const __hip_bfloat16* __restrict__ wtr,
                                    float* __restrict__ Part) {
    constexpr int HO = HS * 2, WO = WS * 2;
    constexpr size_t sliceN = (size_t)8 * HO * WO * CO;
    const int tid = threadIdx.x;
    const int lane = tid & 63, wv = tid >> 6;
    const int r = lane & 15, q = lane >> 4;
    const int pw = WO / 16, ppb = (HO / 16) * pw;
    const int b = blockIdx.x / ppb;
    const int prest = blockIdx.x - b * ppb;
    const int ph = prest / pw, pwi = prest - ph * pw;
    const int oh0 = ph * 16, ow0 = pwi * 16;
    const int sh0 = oh0 >> 1, sw0 = ow0 >> 1;
    const int n0 = blockIdx.y * 64;
    const int ciOff = blockIdx.z * 64;

    __shared__ alignas(16) __hip_bfloat16 Tile[100 * 72];
    __shared__ alignas(16) __hip_bfloat16 Wlds[2][64 * 72];

    f32x4 acc[4][4];
    #pragma unroll
    for (int i = 0; i < 4; ++i)
        #pragma unroll
        for (int j = 0; j < 4; ++j) acc[i][j] = f32x4{0.f, 0.f, 0.f, 0.f};

    for (int i = tid; i < 800; i += 256) {
        int pix = i >> 3, koct = i & 7;
        int tr = pix / 10, tc2 = pix - tr * 10;
        int su = sh0 - 1 + tr, sv = sw0 - 1 + tc2;
        uint4 v = {0, 0, 0, 0};
        if (su >= 0 && su < HS && sv >= 0 && sv < WS)
            v = *(const uint4*)(actIn + ((size_t)((b * HS + su) * WS + sv) * CI + ciOff + koct * 8));
        *(uint4*)&Tile[pix * 72 + koct * 8] = v;
    }
    for (int i = tid; i < 512; i += 256) {
        int co = i >> 3, koct = i & 7;
        *(uint4*)&Wlds[0][co * 72 + koct * 8] =
            *(const uint4*)(wtr + ((size_t)(n0 + co)) * CI + ciOff + koct * 8);
    }
    __syncthreads();

    #pragma unroll 1
    for (int tap = 0; tap < 9; ++tap) {
        const bool pf = (tap < 8);
        uint4 wr0 = {0,0,0,0}, wr1 = {0,0,0,0};
        if (pf) {
            int co0 = tid >> 3, k0 = tid & 7;
            wr0 = *(const uint4*)(wtr + ((size_t)(tap + 1) * CO + n0 + co0) * CI + ciOff + k0 * 8);
            int i1 = tid + 256; int co1 = i1 >> 3, k1 = i1 & 7;
            wr1 = *(const uint4*)(wtr + ((size_t)(tap + 1) * CO + n0 + co1) * CI + ciOff + k1 * 8);
        }
        const int dyv = tap / 3;
        const int dxm1 = tap - dyv * 3 - 1;
        const int tc = ((r + dxm1) >> 1) + 1;
        int apix[4];
        #pragma unroll
        for (int mt = 0; mt < 4; ++mt)
            apix[mt] = ((((wv * 4 + mt) + dyv - 1) >> 1) + 1) * 10 + tc;

        const int buf = tap & 1;
        #pragma unroll
        for (int ch = 0; ch < 2; ++ch) {
            bf16x8 af[4], bfr[4];
            #pragma unroll
            for (int mt = 0; mt < 4; ++mt)
                af[mt] = *(const bf16x8*)&Tile[apix[mt] * 72 + ch * 32 + q * 8];
            #pragma unroll
            for (int nt = 0; nt < 4; ++nt)
                bfr[nt] = *(const bf16x8*)&Wlds[buf][(nt * 16 + r) * 72 + ch * 32 + q * 8];
            #pragma unroll
            for (int mt = 0; mt < 4; ++mt)
                #pragma unroll
                for (int nt = 0; nt < 4; ++nt)
                    acc[mt][nt] = __builtin_amdgcn_mfma_f32_16x16x32_bf16(
                        af[mt], bfr[nt], acc[mt][nt], 0, 0, 0);
        }
        if (pf) {
            int nb = buf ^ 1;
            { int co0 = tid >> 3, k0 = tid & 7;
              *(uint4*)&Wlds[nb][co0 * 72 + k0 * 8] = wr0; }
            { int i1 = tid + 256; int co1 = i1 >> 3, k1 = i1 & 7;
              *(uint4*)&Wlds[nb][co1 * 72 + k1 * 8] = wr1; }
            __syncthreads();
        }
    }

    float* P = Part + (size_t)blockIdx.z * sliceN;
    #pragma unroll
    for (int mt = 0; mt < 4; ++mt) {
        const int prow = wv * 4 + mt;
        #pragma unroll
        for (int t2 = 0; t2 < 4; ++t2) {
            const int pcol = q * 4 + t2;
            const size_t obase = ((size_t)(b * HO + oh0 + prow) * WO + ow0 + pcol) * CO + n0;
            #pragma unroll
            for (int nt = 0; nt < 4; ++nt)
                P[obase + nt * 16 + r] = acc[mt][nt][t2];
        }
    }
}

// sum KS fp32 partial slices -> scale + relu -> bf16 NHWC (unpadded; stages 1-2)
template <int KS, int CO, int HW>
__launch_bounds__(256)
__global__ void reduce_kernel(const float* __restrict__ Part, const float* __restrict__ S,
                              __hip_bfloat16* __restrict__ actOut) {
    constexpr size_t sliceN = (size_t)8 * HW * CO;
    size_t e = ((size_t)blockIdx.x * 256 + threadIdx.x) * 4;
    if (e >= sliceN) return;
    f32x4 sum = {0.f, 0.f, 0.f, 0.f};
    #pragma unroll
    for (int k = 0; k < KS; ++k) sum += *(const f32x4*)(Part + (size_t)k * sliceN + e);
    const int co = (int)(e & (CO - 1));
    const int b = (int)(e / ((size_t)HW * CO));
    const float* Sb = S + b * CO + co;
    union { ushort4 u; __hip_bfloat16 h[4]; } pack;
    #pragma unroll
    for (int j = 0; j < 4; ++j)
        pack.h[j] = __float2bfloat16(fmaxf(sum[j] * Sb[j], 0.f));
    *(ushort4*)((unsigned short*)actOut + e) = pack.u;
}

// stage-3 reduce: KS=2, CO=64, H=W=64 -> writes PADDED act3p [8][66][66][64]
__launch_bounds__(256)
__global__ void reduce_pad_kernel(const float* __restrict__ Part, const float* __restrict__ S,
                                  __hip_bfloat16* __restrict__ actOut) {
    constexpr size_t sliceN = (size_t)8 * 64 * 64 * 64;   // 2097152
    size_t e = ((size_t)blockIdx.x * 256 + threadIdx.x) * 4;
    if (e >= sliceN) return;
    f32x4 sum = *(const f32x4*)(Part + e) + *(const f32x4*)(Part + sliceN + e);
    const int c = (int)(e & 63);
    size_t px = e >> 6;
    const int w = (int)(px & 63);
    const int h = (int)((px >> 6) & 63);
    const int b = (int)(px >> 12);
    const float* Sb = S + b * 64 + c;
    union { ushort4 u; __hip_bfloat16 hh[4]; } pack;
    #pragma unroll
    for (int j = 0; j < 4; ++j)
        pack.hh[j] = __float2bfloat16(fmaxf(sum[j] * Sb[j], 0.f));
    const size_t addr = ((size_t)(b * 66 + h + 1) * 66 + w + 1) * 64 + c;
    *(ushort4*)((unsigned short*)actOut + addr) = pack.u;
}

// ---------------- stages 4/5: role-swapped, pixel-reg-cached, dual-pipe feed ----------------
// actIn  bf16 [8][HS+2][HS+2][64] zero-halo NHWC
// wtr    bf16 [9][64][64]
// actOut bf16 [8][2HS+2][2HS+2][64] (interior written; halo zeroed separately)
// Block: 256 thr / 4 waves; out patch 32 rows x 16 cols; wave = 8 rows.
// MFMA roles: A = weights (m<->co), B = pixels (n<->out col).
// Pixels: register cache, 12 frags/ch from global (L1). Weights: ch0 via LDS, ch1 via global.
template <int HS>
__launch_bounds__(256, 2)
__global__ void conv_up64_kernel(const __hip_bfloat16* __restrict__ actIn,
                                 const __hip_bfloat16* __restrict__ wtr,
                                 const float* __restrict__ S,
                                 __hip_bfloat16* __restrict__ actOut) {
    constexpr int WS = HS, HO = 2 * HS, WO = 2 * WS;
    constexpr int HSp = HS + 2, WSp = WS + 2, HOp = HO + 2, WOp = WO + 2;
    constexpr int WSTR = 40;   // W0 row stride in elements (80 B: 16-B aligned, conflict-free)
    const int tid = threadIdx.x;
    const int lane = tid & 63, wv = tid >> 6;
    const int r = lane & 15, q = lane >> 4;
    const bool rodd = (r & 1) != 0;

    const int ppw = WO / 16, ppb = (HO / 32) * ppw;
    const int b = blockIdx.x / ppb;
    const int rest = blockIdx.x - b * ppb;
    const int ph = rest / ppw, pw_ = rest - ph * ppw;
    const int oh0 = ph * 32, ow0 = pw_ * 16;
    const int sh0 = oh0 >> 1, sw0 = ow0 >> 1;

    __shared__ alignas(16) __hip_bfloat16 W0[9 * 64 * WSTR];   // ch0 half (k 0..31)

    // stage ch0 weights once: item i -> row=i>>2 (tap*64+co), koct=i&3
    for (int i = tid; i < 2304; i += 256) {
        int row = i >> 2, koct = i & 3;
        *(uint4*)&W0[row * WSTR + koct * 8] = *(const uint4*)(wtr + (size_t)row * 64 + koct * 8);
    }
    __syncthreads();

    f32x4 acc[4][8];
    #pragma unroll
    for (int ct = 0; ct < 4; ++ct)
        #pragma unroll
        for (int j = 0; j < 8; ++j) acc[ct][j] = f32x4{0.f, 0.f, 0.f, 0.f};

    const int colbase = sw0 + ((r + 1) >> 1);     // padded col of creg 0
    const size_t inB = (size_t)b * HSp * WSp;

    #pragma unroll
    for (int ch = 0; ch < 2; ++ch) {
        // pixel frag cache: 6 src rows x 2 col-regs (covers all 9 taps x 8 rows)
        bf16x8 P[6][2];
        #pragma unroll
        for (int t = 0; t < 6; ++t) {
            const size_t rowB = (inB + (size_t)(sh0 + 4 * wv + t) * WSp) * 64;
            #pragma unroll
            for (int c = 0; c < 2; ++c)
                P[t][c] = *(const bf16x8*)(actIn + rowB + (size_t)(colbase + c) * 64 + ch * 32 + q * 8);
        }
        #pragma unroll
        for (int dy = 0; dy < 3; ++dy) {
            #pragma unroll
            for (int dx = 0; dx < 3; ++dx) {
                const int tap = dy * 3 + dx;
                bf16x8 wf[4];
                #pragma unroll
                for (int ct = 0; ct < 4; ++ct) {
                    if (ch == 0)
                        wf[ct] = *(const bf16x8*)&W0[(tap * 64 + ct * 16 + r) * WSTR + q * 8];
                    else
                        wf[ct] = *(const bf16x8*)(wtr + ((size_t)tap * 64 + ct * 16 + r) * 64 + 32 + q * 8);
                }
                #pragma unroll
                for (int j = 0; j < 8; ++j) {
                    const int t = (j + dy + 1) >> 1;
                    bf16x8 pb;
                    if (dx == 0)       pb = P[t][0];
                    else if (dx == 2)  pb = P[t][1];
                    else               pb = rodd ? P[t][0] : P[t][1];
                    #pragma unroll
                    for (int ct = 0; ct < 4; ++ct)
                        acc[ct][j] = __builtin_amdgcn_mfma_f32_16x16x32_bf16(
                            wf[ct], pb, acc[ct][j], 0, 0, 0);
                }
            }
        }
    }

    // epilogue: lane holds out[co=ct*16+q*4+t2][col=r] for row j -> packed b64 stores
    const size_t outB = (size_t)b * HOp * WOp;
    #pragma unroll
    for (int ct = 0; ct < 4; ++ct) {
        const f32x4 Sv = *(const f32x4*)(S + b * 64 + ct * 16 + q * 4);
        #pragma unroll
        for (int j = 0; j < 8; ++j) {
            union { unsigned short us[4]; uint2 u2; } pk;
            #pragma unroll
            for (int t2 = 0; t2 < 4; ++t2) {
                __hip_bfloat16 hv = __float2bfloat16(fmaxf(acc[ct][j][t2] * Sv[t2], 0.f));
                pk.us[t2] = *(unsigned short*)&hv;
            }
            const size_t addr = (outB + (size_t)(oh0 + 8 * wv + j + 1) * WOp + (ow0 + r + 1)) * 64
                                + ct * 16 + q * 4;
            *(uint2*)((unsigned short*)actOut + addr) = pk.u2;
        }
    }
}

// ---------------- final conv: 64->3 at 256x256 (padded input), +bias, fp32 NCHW out ----------------
__launch_bounds__(256)
__global__ void conv_final_kernel(const __hip_bfloat16* __restrict__ actIn, // [8][258][258][64]
                                  const __hip_bfloat16* __restrict__ wtr,  // [9][16][64]
                                  const float* __restrict__ bias,
                                  float* __restrict__ out) {               // [8][3][256][256]
    const int tid = threadIdx.x, lane = tid & 63, wv = tid >> 6;
    const int r = lane & 15, q = lane >> 4;

    const int ppb = 32 * 16;
    const int b = blockIdx.x / ppb;
    const int prest = blockIdx.x - b * ppb;
    const int ph = prest >> 4, pwi = prest & 15;
    const int oh0 = ph * 8, ow0 = pwi * 16;

    __shared__ alignas(16) __hip_bfloat16 Tile[10 * 18 * 72];
    __shared__ alignas(16) __hip_bfloat16 Wl[9 * 16 * 72];

    for (int i = tid; i < 1440; i += 256) {
        int pix = i >> 3, koct = i & 7;
        int tr = pix / 18, tc2 = pix - tr * 18;
        uint4 val = *(const uint4*)(actIn +
            ((size_t)((b * 258 + oh0 + tr) * 258) + ow0 + tc2) * 64 + koct * 8);
        *(uint4*)&Tile[pix * 72 + koct * 8] = val;
    }
    for (int i = tid; i < 1152; i += 256) {
        int row = i >> 3, koct = i & 7;
        *(uint4*)&Wl[row * 72 + koct * 8] = *(const uint4*)(wtr + (size_t)row * 64 + koct * 8);
    }
    __syncthreads();

    f32x4 acc[2];
    acc[0] = f32x4{0.f, 0.f, 0.f, 0.f};
    acc[1] = f32x4{0.f, 0.f, 0.f, 0.f};

    #pragma unroll 1
    for (int tap = 0; tap < 9; ++tap) {
        const int dyv = tap / 3;
        const int dxv = tap - dyv * 3;
        const int tc = r + dxv;
        int apix[2];
        #pragma unroll
        for (int mt = 0; mt < 2; ++mt)
            apix[mt] = (wv * 2 + mt + dyv) * 18 + tc;
        #pragma unroll
        for (int ch = 0; ch < 2; ++ch) {
            bf16x8 bfr = *(const bf16x8*)&Wl[(tap * 16 + r) * 72 + ch * 32 + q * 8];
            #pragma unroll
            for (int mt = 0; mt < 2; ++mt) {
                bf16x8 af = *(const bf16x8*)&Tile[apix[mt] * 72 + ch * 32 + q * 8];
                acc[mt] = __builtin_amdgcn_mfma_f32_16x16x32_bf16(af, bfr, acc[mt], 0, 0, 0);
            }
        }
    }

    if (r < 3) {
        const float bs = bias[r];
        #pragma unroll
        for (int mt = 0; mt < 2; ++mt) {
            const int prow = wv * 2 + mt;
            #pragma unroll
            for (int t2 = 0; t2 < 4; ++t2) {
                const int pcol = q * 4 + t2;
                out[((size_t)(b * 3 + r) << 16) + (oh0 + prow) * 256 + ow0 + pcol] =
                    acc[mt][t2] + bs;
            }
        }
    }
}

// ---------------- launch ----------------
extern "C" void kernel_launch(void* const* d_in, const int* in_sizes, int n_in,
                              void* d_out, int out_size, void* d_ws, size_t ws_size,
                              hipStream_t stream) {
    const float* x    = (const float*)d_in[0];
    const float* sty  = (const float*)d_in[1];
    const float* w1   = (const float*)d_in[2];
    const float* fw1  = (const float*)d_in[3];
    const float* fb1  = (const float*)d_in[4];
    const float* w2   = (const float*)d_in[5];
    const float* fw2  = (const float*)d_in[6];
    const float* fb2  = (const float*)d_in[7];
    const float* w3   = (const float*)d_in[8];
    const float* fw3  = (const float*)d_in[9];
    const float* fb3  = (const float*)d_in[10];
    const float* w4   = (const float*)d_in[11];
    const float* fw4  = (const float*)d_in[12];
    const float* fb4  = (const float*)d_in[13];
    const float* w5   = (const float*)d_in[14];
    const float* fw5  = (const float*)d_in[15];
    const float* fb5  = (const float*)d_in[16];
    const float* wf   = (const float*)d_in[17];
    const float* bf   = (const float*)d_in[18];
    float* out = (float*)d_out;

    char* ws = (char*)d_ws;
    size_t off = 0;
    auto alloc = [&](size_t bytes) {
        char* p = ws + off;
        off += (bytes + 255) & ~(size_t)255;
        return p;
    };
    float* S1 = (float*)alloc(8 * 256 * 4);
    float* S2 = (float*)alloc(8 * 128 * 4);
    float* S3 = (float*)alloc(8 * 64 * 4);
    float* S4 = (float*)alloc(8 * 64 * 4);
    float* S5 = (float*)alloc(8 * 64 * 4);
    __hip_bfloat16* act0  = (__hip_bfloat16*)alloc((size_t)262144 * 2);    // 8x8x8x512
    __hip_bfloat16* act1  = (__hip_bfloat16*)alloc((size_t)524288 * 2);    // 8x16x16x256
    __hip_bfloat16* act2  = (__hip_bfloat16*)alloc((size_t)1048576 * 2);   // 8x32x32x128
    __hip_bfloat16* act3p = (__hip_bfloat16*)alloc((size_t)2230272 * 2);   // 8x66x66x64
    __hip_bfloat16* act4p = (__hip_bfloat16*)alloc((size_t)8652800 * 2);   // 8x130x130x64
    __hip_bfloat16* act5p = (__hip_bfloat16*)alloc((size_t)34080768 * 2);  // 8x258x258x64
    __hip_bfloat16* wt1  = (__hip_bfloat16*)alloc((size_t)9 * 256 * 512 * 2);
    __hip_bfloat16* wt2  = (__hip_bfloat16*)alloc((size_t)9 * 128 * 256 * 2);
    __hip_bfloat16* wt3  = (__hip_bfloat16*)alloc((size_t)9 * 64 * 128 * 2);
    __hip_bfloat16* wt4  = (__hip_bfloat16*)alloc((size_t)9 * 64 * 64 * 2);
    __hip_bfloat16* wt5  = (__hip_bfloat16*)alloc((size_t)9 * 64 * 64 * 2);
    __hip_bfloat16* wtF  = (__hip_bfloat16*)alloc((size_t)9 * 16 * 64 * 2);
    // DEDICATED fp32 K-split partial scratch (17 MB). Round-4 bug: this was aliased
    // onto act5p, so conv_partial overwrote the pre-zeroed act5p halo with arbitrary
    // bits (bf16-NaN-capable) that conv_final then read. Keep it separate.
    float* Part = (float*)alloc((size_t)8 * 524288 * 4);   // max over stages: 16.8 MB
    if (off > ws_size) return;

    convert_x_kernel<<<1024, 256, 0, stream>>>(x, act0);
    wtrans_all_kernel<<<6372, 256, 0, stream>>>(w1, wt1, w2, wt2, w3, wt3,
                                                w4, wt4, w5, wt5, wf, wtF);
    style_all_kernel<<<1152, 256, 0, stream>>>(sty, fw1, fb1, fw2, fb2, fw3, fb3,
                                               fw4, fb4, fw5, fb5, S1);
    halo_zero_kernel<<<452, 256, 0, stream>>>(act3p, act4p, act5p);

    // stages 1-3: K-split partials (256 blocks each) + reduce
    conv_partial_kernel<512, 256, 8, 8><<<dim3(8, 4, 8), 256, 0, stream>>>(act0, wt1, Part);
    reduce_kernel<8, 256, 256><<<512, 256, 0, stream>>>(Part, S1, act1);
    conv_partial_kernel<256, 128, 16, 16><<<dim3(32, 2, 4), 256, 0, stream>>>(act1, wt2, Part);
    reduce_kernel<4, 128, 1024><<<1024, 256, 0, stream>>>(Part, S2, act2);
    conv_partial_kernel<128, 64, 32, 32><<<dim3(128, 1, 2), 256, 0, stream>>>(act2, wt3, Part);
    reduce_pad_kernel<<<2048, 256, 0, stream>>>(Part, S3, act3p);

    // stages 4-5: role-swapped dual-pipe kernel (padded in/out)
    conv_up64_kernel<64><<<256, 256, 0, stream>>>(act3p, wt4, S4, act4p);
    conv_up64_kernel<128><<<1024, 256, 0, stream>>>(act4p, wt5, S5, act5p);
    conv_final_kernel<<<4096, 256, 0, stream>>>(act5p, wtF, bf, out);
}